// Round 11
// baseline (619.555 us; speedup 1.0000x reference)
//
#include <hip/hip_runtime.h>
#include <hip/hip_bf16.h>
#include <cstdint>

typedef unsigned short u16;
typedef unsigned int u32;
typedef __attribute__((ext_vector_type(4))) float floatx4;
typedef __attribute__((ext_vector_type(8))) short shortx8;

#define G_STEP 8192
#define N_TOTAL 131072
#define RHALF (1280*256)

__device__ __forceinline__ float bfu2f(u16 x){ return __uint_as_float(((unsigned)x)<<16); }
__device__ __forceinline__ u16 f2bfu(float x){ __hip_bfloat16 b = __float2bfloat16(x); return *reinterpret_cast<u16*>(&b); }
__device__ __forceinline__ float sigm(float x){ return 1.0f/(1.0f+__expf(-x)); }
__device__ __forceinline__ float tanh_(float x){
  float cx = fminf(fmaxf(x,-15.f),15.f);
  float e = __expf(2.f*cx);
  return (e-1.f)/(e+1.f);
}
__device__ __forceinline__ float invs(float x){ return 1.0f/sqrtf(x); }

__device__ __forceinline__ void gl16(const void* g, void* l){
  __builtin_amdgcn_global_load_lds((const __attribute__((address_space(1))) u32*)g,
                                   (__attribute__((address_space(3))) u32*)l, 16, 0, 0);
}

template<int V> __device__ __forceinline__ void wait_vm();
template<> __device__ __forceinline__ void wait_vm<0>(){ asm volatile("s_waitcnt vmcnt(0)" ::: "memory"); }
template<> __device__ __forceinline__ void wait_vm<4>(){ asm volatile("s_waitcnt vmcnt(4)" ::: "memory"); }
template<> __device__ __forceinline__ void wait_vm<5>(){ asm volatile("s_waitcnt vmcnt(5)" ::: "memory"); }
__device__ __forceinline__ void wait_lgkm0(){ asm volatile("s_waitcnt lgkmcnt(0)" ::: "memory"); }

__device__ __forceinline__ void cvt8(const float* __restrict__ src, u16* __restrict__ dst){
  float4 a = *reinterpret_cast<const float4*>(src);
  float4 b = *reinterpret_cast<const float4*>(src+4);
  ushort4 o0; o0.x=f2bfu(a.x); o0.y=f2bfu(a.y); o0.z=f2bfu(a.z); o0.w=f2bfu(a.w);
  ushort4 o1; o1.x=f2bfu(b.x); o1.y=f2bfu(b.y); o1.z=f2bfu(b.z); o1.w=f2bfu(b.w);
  *reinterpret_cast<ushort4*>(dst)   = o0;
  *reinterpret_cast<ushort4*>(dst+4) = o1;
}

// ---------------------------------------------------------------- setup (fused prep + leaf + num_pre + sumsq init)
__global__ __launch_bounds__(256) void setup_kernel(
    const int* __restrict__ tokens, const float* __restrict__ leaf_table,
    const float* __restrict__ W1, const float* __restrict__ b1,
    const float* __restrict__ una_W, const float* __restrict__ bin_W,
    const float* __restrict__ num_W2,
    u16* __restrict__ wbu, u16* __restrict__ wbb, u16* __restrict__ wbn,
    u16* __restrict__ h1, u16* __restrict__ H, u16* __restrict__ C,
    float* __restrict__ sumsq)
{
  const int b = blockIdx.x, tid = threadIdx.x;
  if (b < 256){                                  // wbu: 2048 rows
    int row = b*8 + (tid>>5), d0 = (tid&31)*8;
    int op = row>>10, w = row&1023;
    int gate = (w>>4)&3, e = ((w>>6)<<4) | (w&15);
    cvt8(una_W + (size_t)((op*4+gate)*256 + e)*256 + d0, wbu + (size_t)row*256 + d0);
  } else if (b < 896){                           // wbb: 5120 rows
    int row = (b-256)*8 + (tid>>5), d0 = (tid&31)*8;
    int ob = row / 2560, rem = row - ob*2560;
    int lr = rem / 1280, rw = rem - lr*1280;
    int eblk = rw / 80, rem2 = rw - eblk*80;
    int gate = rem2 >> 4, el = rem2 & 15;
    int e = eblk*16 + el;
    cvt8(bin_W + (size_t)((ob*10 + 2*gate + lr)*256 + e)*256 + d0, wbb + (size_t)row*256 + d0);
  } else if (b < 928){                           // wbn: 256 rows plain
    int row = (b-896)*8 + (tid>>5), d0 = (tid&31)*8;
    cvt8(num_W2 + (size_t)row*256 + d0, wbn + (size_t)row*256 + d0);
  } else if (b < 2976){                          // leaf: 8192 nodes, 4/block
    int wave = tid >> 6, lane = tid & 63;
    int node = (b-928)*4 + wave;
    int t = tokens[node];
    const float4 e4 = *reinterpret_cast<const float4*>(leaf_table + (size_t)t*256 + lane*4);
    float ss = e4.x*e4.x + e4.y*e4.y + e4.z*e4.z + e4.w*e4.w;
    #pragma unroll
    for (int o = 32; o; o >>= 1) ss += __shfl_down(ss, o);
    ss = __shfl(ss, 0);
    float scale = fminf(1.0f, 1.0f/(sqrtf(ss) + 1e-7f));
    ushort4 hv;
    hv.x = f2bfu(e4.x*scale); hv.y = f2bfu(e4.y*scale);
    hv.z = f2bfu(e4.z*scale); hv.w = f2bfu(e4.w*scale);
    ushort4 zv; zv.x = zv.y = zv.z = zv.w = 0;
    *reinterpret_cast<ushort4*>(H + (size_t)node*256 + lane*4) = hv;
    *reinterpret_cast<ushort4*>(C + (size_t)node*256 + lane*4) = zv;
  } else if (b < 4000){                          // num_pre: 2M elems, 8/thread
    int flat = (b-2976)*2048 + tid*8;
    int n = flat >> 8, d0 = flat & 255;
    float x = (float)tokens[G_STEP + n];
    float4 w0 = *reinterpret_cast<const float4*>(W1 + d0);
    float4 w1 = *reinterpret_cast<const float4*>(W1 + d0 + 4);
    float4 c0 = *reinterpret_cast<const float4*>(b1 + d0);
    float4 c1 = *reinterpret_cast<const float4*>(b1 + d0 + 4);
    ushort4 o0, o1;
    o0.x = f2bfu(sigm(x*w0.x + c0.x)); o0.y = f2bfu(sigm(x*w0.y + c0.y));
    o0.z = f2bfu(sigm(x*w0.z + c0.z)); o0.w = f2bfu(sigm(x*w0.w + c0.w));
    o1.x = f2bfu(sigm(x*w1.x + c1.x)); o1.y = f2bfu(sigm(x*w1.y + c1.y));
    o1.z = f2bfu(sigm(x*w1.z + c1.z)); o1.w = f2bfu(sigm(x*w1.w + c1.w));
    *reinterpret_cast<ushort4*>(h1 + flat)     = o0;
    *reinterpret_cast<ushort4*>(h1 + flat + 4) = o1;
  } else {                                       // sumsq init
    if (tid < 32) sumsq[tid] = ((tid & 15) < 2) ? 1.0f : 0.0f;
  }
}

// ---------------------------------------------------------------- fused GEMM + LSTM cell, deferred H-norm
// OCCUPANCY build: 4-wave blocks, 128 x {128|160} tile, BK=32 dbuf ->
// LDS 33-37 KB, VGPR <=170 (__launch_bounds__(256,3)) -> 3 blocks/CU =
// 12 waves/CU (vs 8 in all prior variants).  R5-proven 2-deep counted-vmcnt
// pipeline.  Binary: single acc + half-K boundary rescale acc*=sl/sr
// (R6-verified numerics), epilogue scales by sr.
template<int MODE>
__global__ __launch_bounds__(256, 3) void gemm_fused(
    const u16* __restrict__ Asrc, const int* __restrict__ lidx,
    const int* __restrict__ ridx, const u16* __restrict__ Wb,
    const float* __restrict__ bias, const u16* __restrict__ Cin,
    float* __restrict__ sumsq, u16* __restrict__ H, u16* __restrict__ C,
    int sbase, int step)
{
  constexpr int NG  = (MODE==0) ? 1 : (MODE==1 ? 4 : 5);
  constexpr int NBR = (MODE==2) ? 160 : 128;   // B tile rows (= out cols)
  constexpr int NT  = (MODE==2) ? 16 : 8;      // K tiles of 32
  constexpr int WN  = (MODE==2) ? 80 : 64;     // wave col extent
  constexpr int NFR = WN/16;
  constexpr int NBG = NBR/16;                  // B granules (16 rows x 32 cols)

  __shared__ u16 SA[2][128][32];               // 16 KB
  __shared__ u16 SB[2][NBR][32];               // 16/20 KB
  __shared__ float red[8];

  const int tid  = threadIdx.x;
  const int lane = tid & 63, wave = tid >> 6;

  // XCD-affine bijective swizzle: all by of one bx share an XCD
  const int bid = blockIdx.x;
  const int jj  = bid >> 3;
  const int bx  = (bid & 7) + 8*(jj & 7);      // [0,64)
  const int by  = jj >> 3;
  const int mbase = bx*128;
  const int nbase = by*NBR;

  const int l15 = lane & 15, kg = lane >> 4;
  const int wm = (wave >> 1)*64, wn = (wave & 1)*WN;

  // staging: one gl16 granule = 16 rows x 32 cols; lane l -> row (l>>2),
  // phys 16B-chunk l&3 stores logical chunk (l&3)^(row&3)  [pre-swizzle]
  const int srow = lane >> 2;
  const int sch  = ((lane & 3) ^ (srow & 3)) * 8;   // u16 offset in source row

  // A granules: 8, 2 per wave
  const u16 *aL[2], *aR[2];
  #pragma unroll
  for (int g = 0; g < 2; g++){
    int r = (wave*2 + g)*16 + srow;
    int gr;
    if constexpr (MODE==0) gr = mbase + r;
    else                   gr = lidx[sbase + mbase + r];
    aL[g] = Asrc + (size_t)gr*256 + sch;
    if constexpr (MODE==2)
      aR[g] = Asrc + (size_t)ridx[sbase + mbase + r]*256 + sch;
  }
  // B granules: NBG (8 or 10); MODE2: waves 0,1 take 3, waves 2,3 take 2
  const int nbg_w = (MODE==2) ? ((wave < 2) ? 3 : 2) : 2;
  const int bg0   = (MODE==2) ? ((wave < 2) ? wave*3 : 6 + (wave-2)*2) : wave*2;
  const u16* bP[3];
  #pragma unroll
  for (int g = 0; g < 3; g++){
    int gg = bg0 + g; if (gg >= NBG) gg = NBG-1;
    bP[g] = Wb + (size_t)(nbase + gg*16 + srow)*256 + sch;
  }

  // per-row boundary rescale factors (MODE2), computed pre-loop from global
  float kfac[(MODE==2)?4:1][(MODE==2)?4:1];
  if constexpr (MODE==2){
    #pragma unroll
    for (int mi = 0; mi < 4; mi++)
      #pragma unroll
      for (int r = 0; r < 4; r++){
        int node = sbase + mbase + wm + mi*16 + kg*4 + r;
        kfac[mi][r] = sqrtf(sumsq[ridx[node] >> 13] / sumsq[lidx[node] >> 13]);
      }
  }

  floatx4 acc[4][NFR];
  #pragma unroll
  for (int i = 0; i < 4; i++)
    #pragma unroll
    for (int j2 = 0; j2 < NFR; j2++) acc[i][j2] = (floatx4)(0.0f);

  auto stage = [&](int t, int buf){
    const int kk = (MODE==2 && t >= 8) ? (t-8)*32 : t*32;
    const bool rh = (MODE==2) && (t >= 8);
    #pragma unroll
    for (int g = 0; g < 2; g++){
      const u16* ga;
      if constexpr (MODE==2){ ga = rh ? aR[g] + kk : aL[g] + kk; }
      else                  { ga = aL[g] + kk; }
      gl16(ga, &SA[buf][(wave*2 + g)*16][0]);
    }
    #pragma unroll
    for (int g = 0; g < 3; g++){
      if (g < nbg_w){
        const u16* gb;
        if constexpr (MODE==2){ gb = rh ? bP[g] + RHALF + kk : bP[g] + kk; }
        else                  { gb = bP[g] + kk; }
        gl16(gb, &SB[buf][(bg0 + g)*16][0]);
      }
    }
  };

  stage(0, 0);
  stage(1, 1);
  if (MODE==2 && wave < 2) asm volatile("s_waitcnt vmcnt(5) lgkmcnt(0)" ::: "memory");
  else                     asm volatile("s_waitcnt vmcnt(4) lgkmcnt(0)" ::: "memory");
  __builtin_amdgcn_s_barrier();

  // per-frag LDS read chunk: logical chunk kg at row with row&3 == l15&3
  const int pco = (kg ^ (l15 & 3)) * 8;

  #pragma unroll
  for (int t = 0; t < NT; t++){
    const int buf = t & 1;
    shortx8 af[4], bfr[NFR];
    #pragma unroll
    for (int i = 0; i < 4; i++)
      af[i] = *reinterpret_cast<const shortx8*>(&SA[buf][wm + i*16 + l15][pco]);
    #pragma unroll
    for (int n = 0; n < NFR; n++)
      bfr[n] = *reinterpret_cast<const shortx8*>(&SB[buf][wn + n*16 + l15][pco]);
    wait_lgkm0();                        // my reads of buf in regs
    __builtin_amdgcn_s_barrier();        // all waves done reading buf
    if (t + 2 < NT) stage(t+2, buf);     // overwrite buf; hidden under MFMAs

    if constexpr (MODE==2){
      if (t == 8){                       // left half done: fold sl/sr into acc
        #pragma unroll
        for (int mi = 0; mi < 4; mi++)
          #pragma unroll
          for (int r = 0; r < 4; r++){
            float k = kfac[mi][r];
            #pragma unroll
            for (int ni = 0; ni < NFR; ni++) acc[mi][ni][r] *= k;
          }
      }
    }

    __builtin_amdgcn_s_setprio(1);
    #pragma unroll
    for (int mi = 0; mi < 4; mi++)
      #pragma unroll
      for (int ni = 0; ni < NFR; ni++)
        acc[mi][ni] = __builtin_amdgcn_mfma_f32_16x16x32_bf16(af[mi], bfr[ni], acc[mi][ni], 0, 0, 0);
    __builtin_amdgcn_s_setprio(0);

    if (t + 1 < NT){
      if (t + 2 < NT){
        if (MODE==2 && wave < 2) wait_vm<5>(); else wait_vm<4>();
      } else wait_vm<0>();
      __builtin_amdgcn_s_barrier();
    }
  }

  // ---------------- fused epilogue ----------------
  if constexpr (MODE == 0){
    float bb[4];
    #pragma unroll
    for (int ni = 0; ni < 4; ni++) bb[ni] = bias[nbase + wn + ni*16 + l15];
    #pragma unroll
    for (int mi = 0; mi < 4; mi++){
      #pragma unroll
      for (int r = 0; r < 4; r++){
        int node = sbase + mbase + wm + mi*16 + kg*4 + r;
        u16* hp = H + (size_t)node*256 + nbase + wn + l15;
        u16* cp = C + (size_t)node*256 + nbase + wn + l15;
        #pragma unroll
        for (int ni = 0; ni < 4; ni++){
          hp[ni*16] = f2bfu(sigm(acc[mi][ni][r] + bb[ni]));
          cp[ni*16] = 0;
        }
      }
    }
  } else {
    const int e = (by*2 + (wave & 1))*16 + l15;
    float bb[NG];
    #pragma unroll
    for (int g = 0; g < NG; g++) bb[g] = bias[g*256 + e];
    float hss = 0.f, css = 0.f;
    #pragma unroll
    for (int mi = 0; mi < 4; mi++){
      #pragma unroll
      for (int r = 0; r < 4; r++){
        int node = sbase + mbase + wm + mi*16 + kg*4 + r;
        int chl = lidx[node];
        float cl = bfu2f(Cin[(size_t)chl*256 + e]) * invs(sumsq[16 + (chl >> 13)]);
        float c2, h2;
        if constexpr (MODE == 1){
          float sl = invs(sumsq[chl >> 13]);
          float i_ = sigm(acc[mi][0][r]*sl + bb[0]);
          float f_ = sigm(acc[mi][1][r]*sl + bb[1]);
          float o_ = sigm(acc[mi][2][r]*sl + bb[2]);
          float u_ = tanh_(acc[mi][3][r]*sl + bb[3]);
          c2 = i_*u_ + f_*cl;
          h2 = o_*tanh_(c2);
        } else {
          int chr = ridx[node];
          float sr = invs(sumsq[chr >> 13]);
          float cr = bfu2f(Cin[(size_t)chr*256 + e]) * invs(sumsq[16 + (chr >> 13)]);
          float i_ = sigm(acc[mi][0][r]*sr + bb[0]);
          float fl = sigm(acc[mi][1][r]*sr + bb[1]);
          float fr = sigm(acc[mi][2][r]*sr + bb[2]);
          float o_ = sigm(acc[mi][3][r]*sr + bb[3]);
          float u_ = tanh_(acc[mi][4][r]*sr + bb[4]);
          c2 = i_*u_ + fl*cl + fr*cr;
          h2 = o_*tanh_(c2);
        }
        H[(size_t)node*256 + e] = f2bfu(h2);
        C[(size_t)node*256 + e] = f2bfu(c2);
        hss += h2*h2;
        css += c2*c2;
      }
    }
    #pragma unroll
    for (int o = 32; o; o >>= 1){ hss += __shfl_down(hss, o); css += __shfl_down(css, o); }
    if (lane == 0){ red[wave] = hss; red[4+wave] = css; }
    __syncthreads();
    if (tid == 0)  atomicAdd(&sumsq[step],      red[0]+red[1]+red[2]+red[3]);
    if (tid == 64) atomicAdd(&sumsq[16 + step], red[4]+red[5]+red[6]+red[7]);
  }
}

// ---------------------------------------------------------------- output: bf16->f32 with per-step H scale
__global__ __launch_bounds__(256) void out_kernel(
    const u16* __restrict__ H, const float* __restrict__ sumsq, float* __restrict__ out)
{
  size_t base = ((size_t)blockIdx.x*256 + threadIdx.x)*8;
  int n = (int)(base >> 8);
  float s = invs(sumsq[n >> 13]);
  const uint4 v = *reinterpret_cast<const uint4*>(H + base);
  float4 o0, o1;
  o0.x = bfu2f((u16)(v.x & 0xffff))*s; o0.y = bfu2f((u16)(v.x >> 16))*s;
  o0.z = bfu2f((u16)(v.y & 0xffff))*s; o0.w = bfu2f((u16)(v.y >> 16))*s;
  o1.x = bfu2f((u16)(v.z & 0xffff))*s; o1.y = bfu2f((u16)(v.z >> 16))*s;
  o1.z = bfu2f((u16)(v.w & 0xffff))*s; o1.w = bfu2f((u16)(v.w >> 16))*s;
  *reinterpret_cast<float4*>(out + base)     = o0;
  *reinterpret_cast<float4*>(out + base + 4) = o1;
}

// ---------------------------------------------------------------- host
extern "C" void kernel_launch(void* const* d_in, const int* in_sizes, int n_in,
                              void* d_out, int out_size, void* d_ws, size_t ws_size,
                              hipStream_t stream)
{
  const int*   tokens     = (const int*)d_in[0];
  const int*   lidx       = (const int*)d_in[1];
  const int*   ridx       = (const int*)d_in[2];
  const float* leaf_table = (const float*)d_in[6];
  const float* num_W1     = (const float*)d_in[7];
  const float* num_b1     = (const float*)d_in[8];
  const float* num_W2     = (const float*)d_in[9];
  const float* num_b2     = (const float*)d_in[10];
  const float* una_W      = (const float*)d_in[11];
  const float* una_b      = (const float*)d_in[12];
  const float* bin_W      = (const float*)d_in[13];
  const float* bin_b      = (const float*)d_in[14];

  // ws layout: H | wbu | wbb | wbn | h1 | sumsq
  char* ws = (char*)d_ws;
  size_t off = 0;
  u16* H   = (u16*)(ws + off); off += (size_t)N_TOTAL*256*2;
  u16* wbu = (u16*)(ws + off); off += (size_t)2048*256*2;
  u16* wbb = (u16*)(ws + off); off += (size_t)5120*256*2;
  u16* wbn = (u16*)(ws + off); off += (size_t)256*256*2;
  u16* h1  = (u16*)(ws + off); off += (size_t)G_STEP*256*2;
  float* sumsq = (float*)(ws + off); off += 32*4;

  u16* C = (u16*)d_out;  // dead before out_kernel overwrites

  setup_kernel<<<4001, 256, 0, stream>>>(tokens, leaf_table, num_W1, num_b1,
                                         una_W, bin_W, num_W2,
                                         wbu, wbb, wbn, h1, H, C, sumsq);
  gemm_fused<0><<<128, 256, 0, stream>>>(
      h1, nullptr, nullptr, wbn, num_b2, nullptr, sumsq, H, C, G_STEP, 1);

  const int sched[16] = {-1,-2,0,2,1,3,0,2,1,3,0,2,1,3,0,2};
  for (int d = 2; d < 16; d++){
    int op = sched[d];
    int sbase = d*G_STEP;
    if (op == 0 || op == 1){
      gemm_fused<1><<<512, 256, 0, stream>>>(
          H, lidx, nullptr, wbu + (size_t)op*1024*256,
          una_b + (size_t)op*4*256, C, sumsq, H, C, sbase, d);
    } else {
      int o2 = op - 2;
      gemm_fused<2><<<512, 256, 0, stream>>>(
          H, lidx, ridx, wbb + (size_t)o2*2*1280*256,
          bin_b + (size_t)o2*5*256, C, sumsq, H, C, sbase, d);
    }
  }
  out_kernel<<<(N_TOTAL*256)/(256*8), 256, 0, stream>>>(H, sumsq, (float*)d_out);
}